// Round 17
// baseline (93.382 us; speedup 1.0000x reference)
//
#include <hip/hip_runtime.h>
#include <math.h>

// QuGCN pipeline v16 — TWO launches, de-duplicated stage-2:
//   K1 build_rows4w : 512 blk x 256 thr (2 waves/SIMD). Block (h,o) simulates
//                     the INVERSE of half-circuit h on basis e_o (1 amp/thread)
//                     -> conj(row o of Uh); coalesced bf16 row emission:
//                       U1bf [512 x 256]  rows: Re(U1) then Im(U1)
//                       U2bf [512 x 256]  rows: Re(U2) then Im(U2)  (no dup)
//                     [R13-verified; only the h==1 emission format changed]
//   K2 eval_chain2  : 256 blk x 1024 thr: y = U1*x (MFMA) -> Ys [yr;yi] LDS,
//                     amps_r = Re2*yr - Im2*yi ; amps_i = Re2*yi + Im2*yr
//                     (two K=256 MFMA chains; -yi via bf16 sign-flip),
//                     fused |amp|^2 -> <Z_q> -> norm -> linear head.
//                     [epilogue s-mapping verbatim R13/R16]

namespace {

constexpr int NSAMP = 4096;
constexpr int NW_L  = 132;

// ---------- compile-time trig ----------
constexpr double PI_D   = 3.14159265358979323846264338327950288;
constexpr double TWO_PI = 6.28318530717958647692528676655900577;

constexpr double red_pm_pi(double x) {
  double k = x / TWO_PI;
  long long ki = (long long)k;
  double r = x - (double)ki * TWO_PI;
  if (r > PI_D)  r -= TWO_PI;
  if (r < -PI_D) r += TWO_PI;
  return r;
}
constexpr double csin(double x) {
  double r = red_pm_pi(x), r2 = r * r, term = r, sum = r;
  for (int n = 1; n <= 13; ++n) { term *= -r2 / (double)((2*n)*(2*n+1)); sum += term; }
  return sum;
}
constexpr double ccos(double x) {
  double r = red_pm_pi(x), r2 = r * r, term = 1.0, sum = 1.0;
  for (int n = 1; n <= 13; ++n) { term *= -r2 / (double)((2*n-1)*(2*n)); sum += term; }
  return sum;
}

constexpr int PC[28] = {0,1,2,3,4,5,6, 0,1,2,3,4,5, 0,1,2,3,4, 0,1,2,3, 0,1,2, 0,1, 0};
constexpr int PT[28] = {1,2,3,4,5,6,7, 2,3,4,5,6,7, 3,4,5,6,7, 4,5,6,7, 5,6,7, 6,7, 7};

struct Tbl28 { float c[28]; float s[28]; };
constexpr Tbl28 mk_tbl(int base) {
  Tbl28 t{};
  for (int i = 0; i < 28; ++i) {
    double a = 0.5 * (double)(base + i);
    t.c[i] = (float)ccos(a);
    t.s[i] = (float)csin(a);
  }
  return t;
}
constexpr Tbl28 T_CRY = mk_tbl(8);
constexpr Tbl28 T_CRX = mk_tbl(52);

struct DTbl { float v[512]; };
constexpr DTbl mk_dcrz() {
  DTbl t{};
  for (int s = 0; s < 256; ++s) {
    double psi = 0.0;
    for (int i = 0; i < 28; ++i) {
      const int pc = 7 - PC[i], pt = 7 - PT[i];
      if ((s >> pc) & 1) {
        const double half = 0.5 * (double)(96 + i);
        psi += ((s >> pt) & 1) ? half : -half;
      }
    }
    t.v[2*s]   = (float)ccos(psi);
    t.v[2*s+1] = (float)csin(psi);
  }
  return t;
}
__device__ constexpr DTbl D_CRZ = mk_dcrz();

// ---------- single-amp cross-lane xor on lane bit p (0..5) [verified R12] ----------
__device__ __forceinline__ float shx1(float v, int p) {
  if (p == 0) {
    int r = __builtin_amdgcn_update_dpp((int)__float_as_uint(v), (int)__float_as_uint(v),
                                        0xB1, 0xF, 0xF, true);
    return __uint_as_float((unsigned)r);
  }
  if (p == 1) {
    int r = __builtin_amdgcn_update_dpp((int)__float_as_uint(v), (int)__float_as_uint(v),
                                        0x4E, 0xF, 0xF, true);
    return __uint_as_float((unsigned)r);
  }
  if (p == 2) return __uint_as_float((unsigned)__builtin_amdgcn_ds_swizzle(
                      (int)__float_as_uint(v), 0x101F));   // xor 4
  if (p == 3) return __uint_as_float((unsigned)__builtin_amdgcn_ds_swizzle(
                      (int)__float_as_uint(v), 0x201F));   // xor 8
  if (p == 4) return __uint_as_float((unsigned)__builtin_amdgcn_ds_swizzle(
                      (int)__float_as_uint(v), 0x401F));   // xor 16
  return __shfl_xor(v, 32, 64);
}

// ---------- single-amp gate appliers [verified R12/R13; xw double-buffered R16] ----------
__device__ __forceinline__ void gen_lane(float& ar, float& ai, int s, int p,
                                         float m00r, float m00i, float m01r, float m01i) {
  const int b = (s >> p) & 1;
  const float dr = m00r;
  const float di = b ? -m00i : m00i;
  const float g  = b ? -m01r : m01r;
  const float hh = m01i;
  const float pr = shx1(ar, p);
  const float pi = shx1(ai, p);
  const float mr = ar, mi = ai;
  ar = dr*mr - di*mi + g*pr - hh*pi;
  ai = dr*mi + di*mr + g*pi + hh*pr;
}
__device__ __forceinline__ void gen_xw(float& ar, float& ai, int s, int p,
                                       float m00r, float m00i, float m01r, float m01i,
                                       float2* buf) {
  buf[s] = make_float2(ar, ai);
  __syncthreads();
  const float2 pt = buf[s ^ (1 << p)];
  const int b = (s >> p) & 1;
  const float dr = m00r;
  const float di = b ? -m00i : m00i;
  const float g  = b ? -m01r : m01r;
  const float hh = m01i;
  const float mr = ar, mi = ai;
  ar = dr*mr - di*mi + g*pt.x - hh*pt.y;
  ai = dr*mi + di*mr + g*pt.y + hh*pt.x;
}
__device__ __forceinline__ void cry_lane(float& ar, float& ai, int s, int pc, int pt,
                                         float cc, float sc) {
  const int ctrl = (s >> pc) & 1;
  const float ce = ctrl ? cc : 1.0f;
  float se = ((s >> pt) & 1) ? sc : -sc;
  se = ctrl ? se : 0.0f;
  const float pr = shx1(ar, pt);
  const float pi = shx1(ai, pt);
  ar = ce*ar + se*pr;
  ai = ce*ai + se*pi;
}
__device__ __forceinline__ void cry_xw(float& ar, float& ai, int s, int pc, int pt,
                                       float cc, float sc, float2* buf) {
  buf[s] = make_float2(ar, ai);
  __syncthreads();
  const float2 p = buf[s ^ (1 << pt)];
  const int ctrl = (s >> pc) & 1;
  const float ce = ctrl ? cc : 1.0f;
  float se = ((s >> pt) & 1) ? sc : -sc;
  se = ctrl ? se : 0.0f;
  ar = ce*ar + se*p.x;
  ai = ce*ai + se*p.y;
}
__device__ __forceinline__ void crx_lane(float& ar, float& ai, int s, int pc, int pt,
                                         float cc, float sc) {
  const int ctrl = (s >> pc) & 1;
  const float ce = ctrl ? cc : 1.0f;
  const float se = ctrl ? sc : 0.0f;
  const float pr = shx1(ar, pt);
  const float pi = shx1(ai, pt);
  ar = ce*ar + se*pi;
  ai = ce*ai - se*pr;
}
__device__ __forceinline__ void crx_xw(float& ar, float& ai, int s, int pc, int pt,
                                       float cc, float sc, float2* buf) {
  buf[s] = make_float2(ar, ai);
  __syncthreads();
  const float2 p = buf[s ^ (1 << pt)];
  const int ctrl = (s >> pc) & 1;
  const float ce = ctrl ? cc : 1.0f;
  const float se = ctrl ? sc : 0.0f;
  ar = ce*ar + se*p.y;
  ai = ce*ai - se*p.x;
}

__device__ __forceinline__ unsigned short f2bf(float f) {
  unsigned int u = __float_as_uint(f);
  u = (u + 0x7FFFu + ((u >> 16) & 1u)) >> 16;
  return (unsigned short)u;
}

typedef __attribute__((ext_vector_type(8))) short bf16x8;
typedef __attribute__((ext_vector_type(4))) float f32x4;
typedef __attribute__((ext_vector_type(4))) unsigned int u32x4;

} // namespace

// ---------------- K1: inverse-sim rows, 4 waves/state, coalesced bf16 emit ----------------
// block = (half h, row o); thread s = tid holds conj(Uh[o][s]) at the end.
// [R13-verified; double-buffered xw from R16; h==1 now emits non-duplicated U2]
__global__ __launch_bounds__(256) void build_rows4w(const float* __restrict__ qw,
                                                    unsigned short* __restrict__ U1bf,
                                                    unsigned short* __restrict__ U2bf) {
  __shared__ float4 sM[48];
  __shared__ float2 xb[2][256];
  const int tid = threadIdx.x;
  const int h   = blockIdx.x >> 8;
  const int o   = blockIdx.x & 255;
  const int s   = tid;

  if (tid < 48) {
    const int lp  = tid / 24;
    const int rem = tid - lp * 24;
    const int j   = rem >> 3;
    const int q   = rem & 7;
    const int l   = 2 * h + lp;
    float a, bb;
    if (j == 0) {        // M0 = RY(qw[l][q]) * RZ(qw[l-1][124+q])
      a  = qw[l * NW_L + q];
      bb = (l > 0) ? qw[(l - 1) * NW_L + 124 + q] : 0.f;
    } else if (j == 1) { // M1 = RX(44+q) * RY(36+q)
      a  = qw[l * NW_L + 44 + q];
      bb = qw[l * NW_L + 36 + q];
    } else {             // M2 = RZ(88+q) * RX(80+q); RZ dropped at l=3
      a  = (l < 3) ? qw[l * NW_L + 88 + q] : 0.f;
      bb = qw[l * NW_L + 80 + q];
    }
    float sa, ca, sb, cb;
    __sincosf(0.5f * a,  &sa, &ca);
    __sincosf(0.5f * bb, &sb, &cb);
    float4 m;
    if (j == 0)      m = make_float4(ca*cb, -ca*sb, -sa*cb, -sa*sb); // RY*RZ
    else if (j == 1) m = make_float4(ca*cb, -sa*sb, -ca*sb, -sa*cb); // RX*RY
    else             m = make_float4(ca*cb, -sa*cb, -sb*sa, -sb*ca); // RZ*RX
    sM[tid] = m;
  }

  float ar = (s == o) ? 1.f : 0.f;
  float ai = 0.f;
  const float dzr =  D_CRZ.v[2*s];
  const float dzi = -D_CRZ.v[2*s+1];   // conj for the inverse
  __syncthreads();

  int pb = 0;
#pragma unroll 1
  for (int lp = 1; lp >= 0; --lp) {
    const int l    = 2 * h + lp;
    const int base = lp * 24;
    if (l < 3) {
      const float mr = ar, mi = ai;
      ar = mr*dzr - mi*dzi;
      ai = mr*dzi + mi*dzr;
    }
    // M2^-1
#pragma unroll
    for (int q = 0; q < 8; ++q) {
      float4 m = sM[base + 16 + q];
      if (q <= 1) { gen_xw(ar, ai, s, 7 - q, m.x, -m.y, -m.z, -m.w, xb[pb]); pb ^= 1; }
      else        gen_lane(ar, ai, s, 7 - q, m.x, -m.y, -m.z, -m.w);
    }
    // CRX^-1, reversed order
#pragma unroll
    for (int i = 27; i >= 0; --i) {
      const int pc = 7 - PC[i], pt = 7 - PT[i];
      const float cc = T_CRX.c[i], sc = -T_CRX.s[i];
      if (pt == 6) { crx_xw(ar, ai, s, pc, pt, cc, sc, xb[pb]); pb ^= 1; }
      else         crx_lane(ar, ai, s, pc, pt, cc, sc);
    }
    // M1^-1
#pragma unroll
    for (int q = 0; q < 8; ++q) {
      float4 m = sM[base + 8 + q];
      if (q <= 1) { gen_xw(ar, ai, s, 7 - q, m.x, -m.y, -m.z, -m.w, xb[pb]); pb ^= 1; }
      else        gen_lane(ar, ai, s, 7 - q, m.x, -m.y, -m.z, -m.w);
    }
    // CRY^-1, reversed order
#pragma unroll
    for (int i = 27; i >= 0; --i) {
      const int pc = 7 - PC[i], pt = 7 - PT[i];
      const float cc = T_CRY.c[i], sc = -T_CRY.s[i];
      if (pt == 6) { cry_xw(ar, ai, s, pc, pt, cc, sc, xb[pb]); pb ^= 1; }
      else         cry_lane(ar, ai, s, pc, pt, cc, sc);
    }
    // M0^-1
#pragma unroll
    for (int q = 0; q < 8; ++q) {
      float4 m = sM[base + q];
      if (q <= 1) { gen_xw(ar, ai, s, 7 - q, m.x, -m.y, -m.z, -m.w, xb[pb]); pb ^= 1; }
      else        gen_lane(ar, ai, s, 7 - q, m.x, -m.y, -m.z, -m.w);
    }
  }

  // state = conj(row o of Uh): Re = ar, Im = -ai. Rows: [Re(0..255); Im(0..255)].
  unsigned short* Ub = h ? U2bf : U1bf;
  Ub[(size_t)o * 256 + s]         = f2bf(ar);
  Ub[(size_t)(o + 256) * 256 + s] = f2bf(-ai);
}

// ---------------- K2: y = U1 x ; amps = U2 y (de-dup) ; fused epilogue ----------------
__global__ __launch_bounds__(1024) void eval_chain2(const float* __restrict__ x,
                                                    const unsigned short* __restrict__ U1bf,
                                                    const unsigned short* __restrict__ U2bf,
                                                    const float* __restrict__ fcw,
                                                    const float* __restrict__ fcb,
                                                    float* __restrict__ out) {
  __shared__ unsigned short Xs[16 * 264];   // [col][k 0..255] bf16
  __shared__ unsigned short Ys[16 * 520];   // [col][yr 0..255 ; yi 256..511] bf16
  __shared__ float Zp[16][16][9];
  __shared__ float Zf[16][9];
  const int tid  = threadIdx.x;
  const int lane = tid & 63;
  const int w    = tid >> 6;                // 0..15
  const int colbase = blockIdx.x * 16;

  {
    const int k  = tid >> 2;
    const int c4 = (tid & 3) * 4;
    const float4 v = *(const float4*)(x + (size_t)k * NSAMP + colbase + c4);
    Xs[(c4 + 0) * 264 + k] = f2bf(v.x);
    Xs[(c4 + 1) * 264 + k] = f2bf(v.y);
    Xs[(c4 + 2) * 264 + k] = f2bf(v.z);
    Xs[(c4 + 3) * 264 + k] = f2bf(v.w);
  }
  __syncthreads();

  const int quad = lane >> 4;
  const int n    = lane & 15;
  const int rowb = w * 32;

  // ---- stage 1: y = U1 * x (stacked 512 x 16, K=256) [R13 verbatim] ----
  {
    f32x4 a1[2];
    a1[0] = (f32x4){0.f, 0.f, 0.f, 0.f};
    a1[1] = (f32x4){0.f, 0.f, 0.f, 0.f};
#pragma unroll
    for (int kt = 0; kt < 8; ++kt) {
      const bf16x8 bfrag = *(const bf16x8*)&Xs[n * 264 + kt * 32 + quad * 8];
#pragma unroll
      for (int rt = 0; rt < 2; ++rt) {
        const int row = rowb + rt * 16 + n;
        const bf16x8 afrag = *(const bf16x8*)(U1bf + (size_t)row * 256 + kt * 32 + quad * 8);
        a1[rt] = __builtin_amdgcn_mfma_f32_16x16x32_bf16(afrag, bfrag, a1[rt], 0, 0, 0);
      }
    }
#pragma unroll
    for (int rt = 0; rt < 2; ++rt) {
      unsigned short p4[4];
#pragma unroll
      for (int reg = 0; reg < 4; ++reg) p4[reg] = f2bf(a1[rt][reg]);
      *(uint2*)&Ys[n * 520 + rowb + rt * 16 + quad * 4] = *(const uint2*)p4;
    }
  }
  __syncthreads();

  // ---- stage 2: amps (stacked) via two K=256 chains, U2 non-duplicated ----
  // w<8 (amps_r rows o=rowb..): acc = Re2[o]*yr + Im2[o]*(-yi)
  // w>=8 (amps_i rows o=rowb-256..): acc = Re2[o]*yi + Im2[o]*yr
  const int o0 = (rowb & 255);
  const int offA = (w < 8) ? 0 : 256;     // first-chain B offset: yr | yi
  const int offB = (w < 8) ? 256 : 0;     // second-chain B offset: yi | yr
  const unsigned negmask = (w < 8) ? 0x80008000u : 0u;  // negate yi for r-waves
  f32x4 acc[2];
  acc[0] = (f32x4){0.f, 0.f, 0.f, 0.f};
  acc[1] = (f32x4){0.f, 0.f, 0.f, 0.f};
#pragma unroll
  for (int kt = 0; kt < 8; ++kt) {
    const bf16x8 bf1 = *(const bf16x8*)&Ys[n * 520 + offA + kt * 32 + quad * 8];
#pragma unroll
    for (int rt = 0; rt < 2; ++rt) {
      const int row = o0 + rt * 16 + n;                     // Re2 rows 0..255
      const bf16x8 afrag = *(const bf16x8*)(U2bf + (size_t)row * 256 + kt * 32 + quad * 8);
      acc[rt] = __builtin_amdgcn_mfma_f32_16x16x32_bf16(afrag, bf1, acc[rt], 0, 0, 0);
    }
  }
#pragma unroll
  for (int kt = 0; kt < 8; ++kt) {
    union { bf16x8 h; u32x4 u; } t;
    t.h = *(const bf16x8*)&Ys[n * 520 + offB + kt * 32 + quad * 8];
    t.u ^= (u32x4){negmask, negmask, negmask, negmask};
#pragma unroll
    for (int rt = 0; rt < 2; ++rt) {
      const int row = 256 + o0 + rt * 16 + n;               // Im2 rows 256..511
      const bf16x8 afrag = *(const bf16x8*)(U2bf + (size_t)row * 256 + kt * 32 + quad * 8);
      acc[rt] = __builtin_amdgcn_mfma_f32_16x16x32_bf16(afrag, t.h, acc[rt], 0, 0, 0);
    }
  }

  // epilogue (verified R7-R16): s = (w&7)*32 + rt*16 + quad*4 + reg
  float za[9];
#pragma unroll
  for (int i = 0; i < 9; ++i) za[i] = 0.f;
  const float m4 = (lane & 32) ? -1.f : 1.f;   // s bit3 = quad bit1
  const float m5 = (lane & 16) ? -1.f : 1.f;   // s bit2 = quad bit0
#pragma unroll
  for (int rt = 0; rt < 2; ++rt) {
#pragma unroll
    for (int reg = 0; reg < 4; ++reg) {
      const float v = acc[rt][reg];
      const float p = v * v;
      za[0] += p;
      za[1] += (w & 4)   ? -p : p;   // q0: s bit7
      za[2] += (w & 2)   ? -p : p;   // q1: s bit6
      za[3] += (w & 1)   ? -p : p;   // q2: s bit5
      za[4] += rt        ? -p : p;   // q3: s bit4
      za[5] = fmaf(m4, p, za[5]);    // q4
      za[6] = fmaf(m5, p, za[6]);    // q5
      za[7] += (reg & 2) ? -p : p;   // q6: s bit1
      za[8] += (reg & 1) ? -p : p;   // q7: s bit0
    }
  }
#pragma unroll
  for (int off = 16; off <= 32; off <<= 1) {
#pragma unroll
    for (int i = 0; i < 9; ++i) za[i] += __shfl_xor(za[i], off, 64);
  }
  if (lane < 16) {
#pragma unroll
    for (int i = 0; i < 9; ++i) Zp[w][lane][i] = za[i];
  }
  __syncthreads();

  if (tid < 144) {
    const int col = tid / 9, q = tid - col * 9;
    float z = 0.f;
#pragma unroll
    for (int ww = 0; ww < 16; ++ww) z += Zp[ww][col][q];
    Zf[col][q] = z;
  }
  __syncthreads();

  if (tid < 112) {
    const int col = tid / 7, oo = tid - col * 7;
    const float inv = 1.f / Zf[col][0];
    float v = fcb[oo];
#pragma unroll
    for (int q = 0; q < 8; ++q)
      v = fmaf(fcw[oo * 8 + q], Zf[col][1 + q] * inv, v);
    out[(size_t)(colbase + col) * 7 + oo] = v;
  }
}

extern "C" void kernel_launch(void* const* d_in, const int* in_sizes, int n_in,
                              void* d_out, int out_size, void* d_ws, size_t ws_size,
                              hipStream_t stream) {
  const float* x   = (const float*)d_in[0];   // [256, 4096]
  const float* qw  = (const float*)d_in[1];   // [4, 132]
  const float* fcw = (const float*)d_in[2];   // [7, 8]
  const float* fcb = (const float*)d_in[3];   // [7]
  float* out = (float*)d_out;                 // [4096, 7]

  unsigned short* U1bf = (unsigned short*)d_ws;        // 512x256 bf16 (256 KB)
  unsigned short* U2bf = U1bf + (size_t)512 * 256;     // 512x256 bf16 (256 KB)

  hipLaunchKernelGGL(build_rows4w, dim3(512), dim3(256),  0, stream, qw, U1bf, U2bf);
  hipLaunchKernelGGL(eval_chain2,  dim3(256), dim3(1024), 0, stream,
                     x, U1bf, U2bf, fcw, fcb, out);
}

// Round 18
// 88.166 us; speedup vs baseline: 1.0592x; 1.0592x over previous
//
#include <hip/hip_runtime.h>
#include <math.h>

// QuGCN pipeline v17 = R16 (best, 88.9 us) + double-buffered combine_u
// (16 -> 8 barriers; same strictly-subtractive trick that won R16's build).
//   K1 build_half4w : 512 blk x 256 thr (2048 waves = 2/SIMD). Block (h,s0)
//                     simulates basis e_{s0} through half h (U = U2*U1, exact
//                     split), 1 complex amp per thread. Bits 0..5 in-wave
//                     (DPP / ds_swizzle / shfl); bits 6,7 via double-buffered
//                     LDS exchange (1 barrier each).
//   K2 combine_u    : U = U2*U1 complex GEMM (fp32), emits bf16 [re;im];
//                     k-tiles double-buffered (1 barrier per tile).
//   K3 eval3        : amps = U*x via mfma_f32_16x16x32_bf16, 16 waves/block,
//                     fused |amp|^2 -> <Z_q> -> norm -> head. [R12/R16 verbatim]

namespace {

constexpr int NSAMP = 4096;
constexpr int NW_L  = 132;

// ---------- compile-time trig ----------
constexpr double PI_D   = 3.14159265358979323846264338327950288;
constexpr double TWO_PI = 6.28318530717958647692528676655900577;

constexpr double red_pm_pi(double x) {
  double k = x / TWO_PI;
  long long ki = (long long)k;
  double r = x - (double)ki * TWO_PI;
  if (r > PI_D)  r -= TWO_PI;
  if (r < -PI_D) r += TWO_PI;
  return r;
}
constexpr double csin(double x) {
  double r = red_pm_pi(x), r2 = r * r, term = r, sum = r;
  for (int n = 1; n <= 13; ++n) { term *= -r2 / (double)((2*n)*(2*n+1)); sum += term; }
  return sum;
}
constexpr double ccos(double x) {
  double r = red_pm_pi(x), r2 = r * r, term = 1.0, sum = 1.0;
  for (int n = 1; n <= 13; ++n) { term *= -r2 / (double)((2*n-1)*(2*n)); sum += term; }
  return sum;
}

constexpr int PC[28] = {0,1,2,3,4,5,6, 0,1,2,3,4,5, 0,1,2,3,4, 0,1,2,3, 0,1,2, 0,1, 0};
constexpr int PT[28] = {1,2,3,4,5,6,7, 2,3,4,5,6,7, 3,4,5,6,7, 4,5,6,7, 5,6,7, 6,7, 7};

struct Tbl28 { float c[28]; float s[28]; };
constexpr Tbl28 mk_tbl(int base) {
  Tbl28 t{};
  for (int i = 0; i < 28; ++i) {
    double a = 0.5 * (double)(base + i);
    t.c[i] = (float)ccos(a);
    t.s[i] = (float)csin(a);
  }
  return t;
}
constexpr Tbl28 T_CRY = mk_tbl(8);
constexpr Tbl28 T_CRX = mk_tbl(52);

struct DTbl { float v[512]; };
constexpr DTbl mk_dcrz() {
  DTbl t{};
  for (int s = 0; s < 256; ++s) {
    double psi = 0.0;
    for (int i = 0; i < 28; ++i) {
      const int pc = 7 - PC[i], pt = 7 - PT[i];
      if ((s >> pc) & 1) {
        const double half = 0.5 * (double)(96 + i);
        psi += ((s >> pt) & 1) ? half : -half;
      }
    }
    t.v[2*s]   = (float)ccos(psi);
    t.v[2*s+1] = (float)csin(psi);
  }
  return t;
}
__device__ constexpr DTbl D_CRZ = mk_dcrz();

// ---------- single-amp cross-lane xor on lane bit p (0..5) [verified R12] ----------
__device__ __forceinline__ float shx1(float v, int p) {
  if (p == 0) {
    int r = __builtin_amdgcn_update_dpp((int)__float_as_uint(v), (int)__float_as_uint(v),
                                        0xB1, 0xF, 0xF, true);
    return __uint_as_float((unsigned)r);
  }
  if (p == 1) {
    int r = __builtin_amdgcn_update_dpp((int)__float_as_uint(v), (int)__float_as_uint(v),
                                        0x4E, 0xF, 0xF, true);
    return __uint_as_float((unsigned)r);
  }
  if (p == 2) return __uint_as_float((unsigned)__builtin_amdgcn_ds_swizzle(
                      (int)__float_as_uint(v), 0x101F));   // xor 4
  if (p == 3) return __uint_as_float((unsigned)__builtin_amdgcn_ds_swizzle(
                      (int)__float_as_uint(v), 0x201F));   // xor 8
  if (p == 4) return __uint_as_float((unsigned)__builtin_amdgcn_ds_swizzle(
                      (int)__float_as_uint(v), 0x401F));   // xor 16
  return __shfl_xor(v, 32, 64);
}

// ---------- single-amp gate appliers [verified R12/R16] ----------
__device__ __forceinline__ void gen_lane(float& ar, float& ai, int s, int p,
                                         float m00r, float m00i, float m01r, float m01i) {
  const int b = (s >> p) & 1;
  const float dr = m00r;
  const float di = b ? -m00i : m00i;
  const float g  = b ? -m01r : m01r;
  const float hh = m01i;
  const float pr = shx1(ar, p);
  const float pi = shx1(ai, p);
  const float mr = ar, mi = ai;
  ar = dr*mr - di*mi + g*pr - hh*pi;
  ai = dr*mi + di*mr + g*pi + hh*pr;
}
__device__ __forceinline__ void gen_xw(float& ar, float& ai, int s, int p,
                                       float m00r, float m00i, float m01r, float m01i,
                                       float2* buf) {
  buf[s] = make_float2(ar, ai);
  __syncthreads();
  const float2 pt = buf[s ^ (1 << p)];
  const int b = (s >> p) & 1;
  const float dr = m00r;
  const float di = b ? -m00i : m00i;
  const float g  = b ? -m01r : m01r;
  const float hh = m01i;
  const float mr = ar, mi = ai;
  ar = dr*mr - di*mi + g*pt.x - hh*pt.y;
  ai = dr*mi + di*mr + g*pt.y + hh*pt.x;
}
__device__ __forceinline__ void cry_lane(float& ar, float& ai, int s, int pc, int pt,
                                         float cc, float sc) {
  const int ctrl = (s >> pc) & 1;
  const float ce = ctrl ? cc : 1.0f;
  float se = ((s >> pt) & 1) ? sc : -sc;
  se = ctrl ? se : 0.0f;
  const float pr = shx1(ar, pt);
  const float pi = shx1(ai, pt);
  ar = ce*ar + se*pr;
  ai = ce*ai + se*pi;
}
__device__ __forceinline__ void cry_xw(float& ar, float& ai, int s, int pc, int pt,
                                       float cc, float sc, float2* buf) {
  buf[s] = make_float2(ar, ai);
  __syncthreads();
  const float2 p = buf[s ^ (1 << pt)];
  const int ctrl = (s >> pc) & 1;
  const float ce = ctrl ? cc : 1.0f;
  float se = ((s >> pt) & 1) ? sc : -sc;
  se = ctrl ? se : 0.0f;
  ar = ce*ar + se*p.x;
  ai = ce*ai + se*p.y;
}
__device__ __forceinline__ void crx_lane(float& ar, float& ai, int s, int pc, int pt,
                                         float cc, float sc) {
  const int ctrl = (s >> pc) & 1;
  const float ce = ctrl ? cc : 1.0f;
  const float se = ctrl ? sc : 0.0f;
  const float pr = shx1(ar, pt);
  const float pi = shx1(ai, pt);
  ar = ce*ar + se*pi;
  ai = ce*ai - se*pr;
}
__device__ __forceinline__ void crx_xw(float& ar, float& ai, int s, int pc, int pt,
                                       float cc, float sc, float2* buf) {
  buf[s] = make_float2(ar, ai);
  __syncthreads();
  const float2 p = buf[s ^ (1 << pt)];
  const int ctrl = (s >> pc) & 1;
  const float ce = ctrl ? cc : 1.0f;
  const float se = ctrl ? sc : 0.0f;
  ar = ce*ar + se*p.y;
  ai = ce*ai - se*p.x;
}

__device__ __forceinline__ unsigned short f2bf(float f) {
  unsigned int u = __float_as_uint(f);
  u = (u + 0x7FFFu + ((u >> 16) & 1u)) >> 16;
  return (unsigned short)u;
}

typedef __attribute__((ext_vector_type(8))) short bf16x8;
typedef __attribute__((ext_vector_type(4))) float f32x4;

} // namespace

// ---------------- K1: build half-circuit unitaries, 4 waves per state [R16 verbatim] ----------------
__global__ __launch_bounds__(256) void build_half4w(const float* __restrict__ qw,
                                                    float* __restrict__ U1c,
                                                    float* __restrict__ U2c) {
  __shared__ float4 sM[48];
  __shared__ float2 xb[2][256];
  const int tid = threadIdx.x;
  const int h   = blockIdx.x >> 8;
  const int s0  = blockIdx.x & 255;
  const int s   = tid;

  if (tid < 48) {
    const int lp  = tid / 24;
    const int rem = tid - lp * 24;
    const int j   = rem >> 3;
    const int q   = rem & 7;
    const int l   = 2 * h + lp;
    float a, bb;
    if (j == 0) {        // M0 = RY(qw[l][q]) * RZ(qw[l-1][124+q])
      a  = qw[l * NW_L + q];
      bb = (l > 0) ? qw[(l - 1) * NW_L + 124 + q] : 0.f;
    } else if (j == 1) { // M1 = RX(44+q) * RY(36+q)
      a  = qw[l * NW_L + 44 + q];
      bb = qw[l * NW_L + 36 + q];
    } else {             // M2 = RZ(88+q) * RX(80+q); RZ dropped at l=3
      a  = (l < 3) ? qw[l * NW_L + 88 + q] : 0.f;
      bb = qw[l * NW_L + 80 + q];
    }
    float sa, ca, sb, cb;
    __sincosf(0.5f * a,  &sa, &ca);
    __sincosf(0.5f * bb, &sb, &cb);
    float4 m;
    if (j == 0)      m = make_float4(ca*cb, -ca*sb, -sa*cb, -sa*sb); // RY*RZ
    else if (j == 1) m = make_float4(ca*cb, -sa*sb, -ca*sb, -sa*cb); // RX*RY
    else             m = make_float4(ca*cb, -sa*cb, -sb*sa, -sb*ca); // RZ*RX
    sM[tid] = m;
  }

  float ar = (s == s0) ? 1.f : 0.f;
  float ai = 0.f;
  const float dzr = D_CRZ.v[2*s];
  const float dzi = D_CRZ.v[2*s+1];
  __syncthreads();

  int pb = 0;
#pragma unroll 1
  for (int lp = 0; lp < 2; ++lp) {
    const int base = lp * 24;
    // M0 block
#pragma unroll
    for (int q = 0; q < 8; ++q) {
      float4 m = sM[base + q];
      if (q <= 1) { gen_xw(ar, ai, s, 7 - q, m.x, m.y, m.z, m.w, xb[pb]); pb ^= 1; }
      else        gen_lane(ar, ai, s, 7 - q, m.x, m.y, m.z, m.w);
    }
    // CRY block
#pragma unroll
    for (int i = 0; i < 28; ++i) {
      const int pc = 7 - PC[i], pt = 7 - PT[i];
      const float cc = T_CRY.c[i], sc = T_CRY.s[i];
      if (pt == 6) { cry_xw(ar, ai, s, pc, pt, cc, sc, xb[pb]); pb ^= 1; }
      else         cry_lane(ar, ai, s, pc, pt, cc, sc);
    }
    // M1 block
#pragma unroll
    for (int q = 0; q < 8; ++q) {
      float4 m = sM[base + 8 + q];
      if (q <= 1) { gen_xw(ar, ai, s, 7 - q, m.x, m.y, m.z, m.w, xb[pb]); pb ^= 1; }
      else        gen_lane(ar, ai, s, 7 - q, m.x, m.y, m.z, m.w);
    }
    // CRX block
#pragma unroll
    for (int i = 0; i < 28; ++i) {
      const int pc = 7 - PC[i], pt = 7 - PT[i];
      const float cc = T_CRX.c[i], sc = T_CRX.s[i];
      if (pt == 6) { crx_xw(ar, ai, s, pc, pt, cc, sc, xb[pb]); pb ^= 1; }
      else         crx_lane(ar, ai, s, pc, pt, cc, sc);
    }
    // M2 block
#pragma unroll
    for (int q = 0; q < 8; ++q) {
      float4 m = sM[base + 16 + q];
      if (q <= 1) { gen_xw(ar, ai, s, 7 - q, m.x, m.y, m.z, m.w, xb[pb]); pb ^= 1; }
      else        gen_lane(ar, ai, s, 7 - q, m.x, m.y, m.z, m.w);
    }
    // CRZ diagonal (dropped at l==3)
    if (2 * h + lp < 3) {
      const float mr = ar, mi = ai;
      ar = mr*dzr - mi*dzi;
      ai = mr*dzi + mi*dzr;
    }
  }

  float* Uc = h ? U2c : U1c;
  ((float2*)(Uc + (size_t)s0 * 512))[s] = make_float2(ar, ai);
}

// ---------------- K2: U = U2 * U1 (complex), emit bf16 — double-buffered k-tiles ----------------
__global__ __launch_bounds__(256) void combine_u(const float* __restrict__ U1c,
                                                 const float* __restrict__ U2c,
                                                 unsigned short* __restrict__ Ubf) {
  __shared__ float2 S2[2][32 * 16];   // [buf][kk][i]
  __shared__ float2 S1[2][16 * 33];   // [buf][j][kk] padded
  const int tid = threadIdx.x;
  const int ti  = tid & 15;
  const int tj  = tid >> 4;
  const int bi  = blockIdx.x & 15;
  const int bj  = blockIdx.x >> 4;

  float accr = 0.f, acci = 0.f;
#pragma unroll 1
  for (int kt = 0; kt < 8; ++kt) {
    const int buf = kt & 1;
    // stage this k-tile (reuse of `buf` is ordered by the PREVIOUS tile's
    // barrier two iterations back — reads of buf at kt-2 precede barrier(kt-1),
    // which precedes these stores)
#pragma unroll
    for (int v = 0; v < 2; ++v) {
      const int s = v * 256 + tid;
      const int k  = s >> 4, i = s & 15;
      S2[buf][k * 16 + i] = *(const float2*)(U2c + (size_t)(kt*32 + k) * 512 + (bi*16 + i) * 2);
      const int j2 = s >> 5, k2 = s & 31;
      S1[buf][j2 * 33 + k2] = *(const float2*)(U1c + (size_t)(bj*16 + j2) * 512 + (kt*32 + k2) * 2);
    }
    __syncthreads();
#pragma unroll
    for (int kk = 0; kk < 32; ++kk) {
      const float2 a = S2[buf][kk * 16 + ti];
      const float2 b = S1[buf][tj * 33 + kk];
      accr = fmaf(a.x, b.x, accr);  accr = fmaf(-a.y, b.y, accr);
      acci = fmaf(a.x, b.y, acci);  acci = fmaf(a.y, b.x, acci);
    }
  }
  const int i = bi * 16 + ti, j = bj * 16 + tj;
  Ubf[(size_t)i * 256 + j]         = f2bf(accr);
  Ubf[(size_t)(i + 256) * 256 + j] = f2bf(acci);
}

// ---------------- K3: eval3 — 16 waves/block, 32 rows/wave [R12/R16 verbatim] ----------------
__global__ __launch_bounds__(1024) void eval3(const float* __restrict__ x,
                                              const unsigned short* __restrict__ Ubf,
                                              const float* __restrict__ fcw,
                                              const float* __restrict__ fcb,
                                              float* __restrict__ out) {
  __shared__ unsigned short Xs[16 * 264];   // [col][k] bf16, padded
  __shared__ float Zp[16][16][9];           // [wave][col][9]
  __shared__ float Zf[16][9];
  const int tid  = threadIdx.x;
  const int lane = tid & 63;
  const int w    = tid >> 6;                // 0..15
  const int colbase = blockIdx.x * 16;

  {
    const int k  = tid >> 2;
    const int c4 = (tid & 3) * 4;
    const float4 v = *(const float4*)(x + (size_t)k * NSAMP + colbase + c4);
    Xs[(c4 + 0) * 264 + k] = f2bf(v.x);
    Xs[(c4 + 1) * 264 + k] = f2bf(v.y);
    Xs[(c4 + 2) * 264 + k] = f2bf(v.z);
    Xs[(c4 + 3) * 264 + k] = f2bf(v.w);
  }
  __syncthreads();

  const int quad = lane >> 4;
  const int n    = lane & 15;
  const int rowb = w * 32;

  f32x4 acc[2];
  acc[0] = (f32x4){0.f, 0.f, 0.f, 0.f};
  acc[1] = (f32x4){0.f, 0.f, 0.f, 0.f};

#pragma unroll
  for (int kt = 0; kt < 8; ++kt) {
    const bf16x8 bfrag = *(const bf16x8*)&Xs[n * 264 + kt * 32 + quad * 8];
#pragma unroll
    for (int rt = 0; rt < 2; ++rt) {
      const int row = rowb + rt * 16 + n;
      const bf16x8 afrag = *(const bf16x8*)(Ubf + (size_t)row * 256 + kt * 32 + quad * 8);
      acc[rt] = __builtin_amdgcn_mfma_f32_16x16x32_bf16(afrag, bfrag, acc[rt], 0, 0, 0);
    }
  }

  float za[9];
#pragma unroll
  for (int i = 0; i < 9; ++i) za[i] = 0.f;
  const float m4 = (lane & 32) ? -1.f : 1.f;   // s bit3 = quad bit1
  const float m5 = (lane & 16) ? -1.f : 1.f;   // s bit2 = quad bit0
#pragma unroll
  for (int rt = 0; rt < 2; ++rt) {
#pragma unroll
    for (int reg = 0; reg < 4; ++reg) {
      const float v = acc[rt][reg];
      const float p = v * v;
      za[0] += p;
      za[1] += (w & 4)   ? -p : p;   // q0: s bit7
      za[2] += (w & 2)   ? -p : p;   // q1: s bit6
      za[3] += (w & 1)   ? -p : p;   // q2: s bit5
      za[4] += rt        ? -p : p;   // q3: s bit4
      za[5] = fmaf(m4, p, za[5]);    // q4
      za[6] = fmaf(m5, p, za[6]);    // q5
      za[7] += (reg & 2) ? -p : p;   // q6: s bit1
      za[8] += (reg & 1) ? -p : p;   // q7: s bit0
    }
  }
#pragma unroll
  for (int off = 16; off <= 32; off <<= 1) {
#pragma unroll
    for (int i = 0; i < 9; ++i) za[i] += __shfl_xor(za[i], off, 64);
  }
  if (lane < 16) {
#pragma unroll
    for (int i = 0; i < 9; ++i) Zp[w][lane][i] = za[i];
  }
  __syncthreads();

  if (tid < 144) {
    const int col = tid / 9, q = tid - col * 9;
    float z = 0.f;
#pragma unroll
    for (int ww = 0; ww < 16; ++ww) z += Zp[ww][col][q];
    Zf[col][q] = z;
  }
  __syncthreads();

  if (tid < 112) {
    const int col = tid / 7, oo = tid - col * 7;
    const float inv = 1.f / Zf[col][0];
    float v = fcb[oo];
#pragma unroll
    for (int q = 0; q < 8; ++q)
      v = fmaf(fcw[oo * 8 + q], Zf[col][1 + q] * inv, v);
    out[(size_t)(colbase + col) * 7 + oo] = v;
  }
}

extern "C" void kernel_launch(void* const* d_in, const int* in_sizes, int n_in,
                              void* d_out, int out_size, void* d_ws, size_t ws_size,
                              hipStream_t stream) {
  const float* x   = (const float*)d_in[0];   // [256, 4096]
  const float* qw  = (const float*)d_in[1];   // [4, 132]
  const float* fcw = (const float*)d_in[2];   // [7, 8]
  const float* fcb = (const float*)d_in[3];   // [7]
  float* out = (float*)d_out;                 // [4096, 7]

  float* U1c = (float*)d_ws;                      // 256x256 complex fp32 (512 KB)
  float* U2c = U1c + 256 * 512;                   // 512 KB
  unsigned short* Ubf = (unsigned short*)(U2c + 256 * 512);  // 512x256 bf16 (256 KB)

  hipLaunchKernelGGL(build_half4w, dim3(512), dim3(256),  0, stream, qw, U1c, U2c);
  hipLaunchKernelGGL(combine_u,    dim3(256), dim3(256),  0, stream, U1c, U2c, Ubf);
  hipLaunchKernelGGL(eval3,        dim3(256), dim3(1024), 0, stream, x, Ubf, fcw, fcb, out);
}